// Round 4
// baseline (838.502 us; speedup 1.0000x reference)
//
#include <hip/hip_runtime.h>
#include <math.h>

#define PW 32
#define PL 64
#define PK 512
#define PN 64
// vectors (replica configurations) total: PW*PL*PK = 1,048,576

// 0/1 mask bit -> f64 1.0/0.0 via scalar cselect (bit pattern of 1.0)
__device__ __forceinline__ double selbit(unsigned long long m, int i) {
    unsigned long long d = ((m >> i) & 1ull) ? 0x3FF0000000000000ull : 0ull;
    return __builtin_bit_cast(double, d);
}

// ---------------- Kernel 1: energies ----------------
// One wave per chunk of VPW vectors (same w). Lane j holds Q[w][:, j]
// (column) as f64 in 64 NAMED register variables (round-3 lesson: a
// double[64] alloca is NOT promoted — VGPR_Count stayed 76 and every qd[i]
// was a scratch load; named scalars force SSA/VGPR residency).
constexpr int VPW = 64;

// q0..q63 declarations
#define DECLQ(i) double q##i = (double)Qw[(i) * 64 + lane];
#define DECLQ8(a,b,c,d,e,f,g,h) DECLQ(a) DECLQ(b) DECLQ(c) DECLQ(d) DECLQ(e) DECLQ(f) DECLQ(g) DECLQ(h)

// accumulate 4 bits into the 4 chains — same i->chain mapping (i&3) and same
// per-chain order as round 3, so f64 results are bit-identical (mask safety).
#define STEP4(i0,i1,i2,i3) \
    a0 = __builtin_fma(selbit(m, i0), q##i0, a0); \
    a1 = __builtin_fma(selbit(m, i1), q##i1, a1); \
    a2 = __builtin_fma(selbit(m, i2), q##i2, a2); \
    a3 = __builtin_fma(selbit(m, i3), q##i3, a3);

__global__ __launch_bounds__(256, 2) void energies_kernel(
    const float* __restrict__ states, const float* __restrict__ Q,
    float* __restrict__ e_out, double* __restrict__ e64)
{
    const int wave = (blockIdx.x * blockDim.x + threadIdx.x) >> 6;
    const int lane = threadIdx.x & 63;
    const int waves_per_w = (PL * PK) / VPW;   // 512
    const int w = wave / waves_per_w;
    const int chunk = wave % waves_per_w;

    const float* Qw = Q + (long)w * PN * PN;
    DECLQ8( 0, 1, 2, 3, 4, 5, 6, 7)
    DECLQ8( 8, 9,10,11,12,13,14,15)
    DECLQ8(16,17,18,19,20,21,22,23)
    DECLQ8(24,25,26,27,28,29,30,31)
    DECLQ8(32,33,34,35,36,37,38,39)
    DECLQ8(40,41,42,43,44,45,46,47)
    DECLQ8(48,49,50,51,52,53,54,55)
    DECLQ8(56,57,58,59,60,61,62,63)

    const long base_v = (long)w * (PL * PK) + (long)chunk * VPW;
    const float* sp = states + base_v * PN + lane;

    float s = sp[0];
    for (int t = 0; t < VPW; ++t) {
        // prefetch next vector's element (independent; scheduler hoists it)
        float snext = (t + 1 < VPW) ? sp[(long)(t + 1) * PN] : 0.0f;

        const unsigned long long m = __ballot(s != 0.0f); // wave-uniform mask

        double a0 = 0.0, a1 = 0.0, a2 = 0.0, a3 = 0.0;
        STEP4( 0, 1, 2, 3)  STEP4( 4, 5, 6, 7)
        STEP4( 8, 9,10,11)  STEP4(12,13,14,15)
        STEP4(16,17,18,19)  STEP4(20,21,22,23)
        STEP4(24,25,26,27)  STEP4(28,29,30,31)
        STEP4(32,33,34,35)  STEP4(36,37,38,39)
        STEP4(40,41,42,43)  STEP4(44,45,46,47)
        STEP4(48,49,50,51)  STEP4(52,53,54,55)
        STEP4(56,57,58,59)  STEP4(60,61,62,63)
        const double colsum = (a0 + a1) + (a2 + a3);

        // lane j contributes only if s_j != 0 ; s is exactly 0.0f or 1.0f
        double e = colsum * (double)s;
#pragma unroll
        for (int off = 32; off > 0; off >>= 1)
            e += __shfl_down(e, off, 64);

        if (lane == 0) {
            e64[base_v + t]   = e;
            e_out[base_v + t] = (float)e;
        }
        s = snext;
    }
}

// ---------------- Kernel 2: exchange masks ----------------
__global__ __launch_bounds__(256) void mask_kernel(
    const double* __restrict__ e64, const float* __restrict__ beta,
    const float* __restrict__ u, unsigned char* __restrict__ mask)
{
    const int idx = blockIdx.x * blockDim.x + threadIdx.x;
    if (idx >= PW * (PL - 1) * PK) return;
    const int k = idx % PK;
    const int m = (idx / PK) % (PL - 1);
    const int w = idx / (PK * (PL - 1));
    const long e1 = ((long)w * PL + m) * PK + k;
    const double db = (double)beta[m + 1] - (double)beta[m];
    const double delta = (e64[e1 + PK] - e64[e1]) * db;
    mask[idx] = ((double)u[idx] < exp(delta)) ? 1 : 0;
}

// ---------------- Kernel 3: masked replica swap ----------------
// new[w,0]   = mask[w,0]   ? s[w,1]   : s[w,0]
// new[w,l>0] = mask[w,l-1] ? s[w,l-1] : s[w,l]
// Block handles 32 consecutive rows (same w,l; k 32-aligned). Source-replica
// indices staged in LDS once; then independent, fully-coalesced float4 copies.
// Total rows = W*L*K = 1,048,576 -> grid = 32768 blocks.
__global__ __launch_bounds__(256) void swap_kernel(
    const float* __restrict__ states, const unsigned char* __restrict__ mask,
    float* __restrict__ out)
{
    const long rowBase = (long)blockIdx.x * 32;     // (w*L + l)*K + k0
    const int w  = (int)(rowBase >> 15);            // / (L*K)
    const int l  = (int)((rowBase >> 9) & 63);
    const int k0 = (int)(rowBase & 511);

    __shared__ int srcl[32];
    const int tid = threadIdx.x;
    if (tid < 32) {
        const int k = k0 + tid;
        int src;
        if (l == 0) {
            const unsigned char mk = mask[(long)w * (PL - 1) * PK + k];
            src = mk ? 1 : 0;
        } else {
            const unsigned char mk = mask[((long)w * (PL - 1) + (l - 1)) * PK + k];
            src = mk ? (l - 1) : l;
        }
        srcl[tid] = src;
    }
    __syncthreads();

    const int j4 = tid & 15;
    const int r0 = tid >> 4;                        // 0..15
#pragma unroll
    for (int h = 0; h < 2; ++h) {
        const int r = r0 + h * 16;                  // row within block, 0..31
        const int k = k0 + r;
        const int sl = srcl[r];
        const float4* srcp = (const float4*)(states + (((long)w * PL + sl) * PK + k) * PN);
        float4*       dstp = (float4*)(out + (rowBase + r) * PN);
        dstp[j4] = srcp[j4];
    }
}

extern "C" void kernel_launch(void* const* d_in, const int* in_sizes, int n_in,
                              void* d_out, int out_size, void* d_ws, size_t ws_size,
                              hipStream_t stream) {
    const float* states = (const float*)d_in[0];
    const float* Q      = (const float*)d_in[1];
    const float* beta   = (const float*)d_in[2];
    const float* u      = (const float*)d_in[3];

    float* e_out      = (float*)d_out;
    float* new_states = (float*)d_out + (long)PW * PL * PK;

    double* e64 = (double*)d_ws;
    unsigned char* mask = (unsigned char*)d_ws + sizeof(double) * (long)PW * PL * PK;

    // K1: 32 w * 512 chunk-waves = 16384 waves -> 4096 blocks of 256
    energies_kernel<<<4096, 256, 0, stream>>>(states, Q, e_out, e64);

    const int nmask = PW * (PL - 1) * PK;
    mask_kernel<<<(nmask + 255) / 256, 256, 0, stream>>>(e64, beta, u, mask);

    // K3: 1,048,576 rows / 32 per block = 32768 blocks
    swap_kernel<<<32768, 256, 0, stream>>>(states, mask, new_states);
}